// Round 1
// baseline (329.010 us; speedup 1.0000x reference)
//
#include <hip/hip_runtime.h>

#define NB 16384
#define ND 512
#define NH 128
#define NHH 256
#define NG 18

typedef short s8v __attribute__((ext_vector_type(8)));
typedef __bf16 bf8v __attribute__((ext_vector_type(8)));
typedef float f4v __attribute__((ext_vector_type(4)));
typedef unsigned int u4v __attribute__((ext_vector_type(4)));

static __device__ __forceinline__ unsigned short f2bf(float f) {
  unsigned int u = __builtin_bit_cast(unsigned int, f);
  u += 0x7FFFu + ((u >> 16) & 1u);
  return (unsigned short)(u >> 16);
}

static __device__ __forceinline__ f4v mfma16(s8v a, s8v b, f4v c) {
  return __builtin_amdgcn_mfma_f32_16x16x32_bf16(
      __builtin_bit_cast(bf8v, a), __builtin_bit_cast(bf8v, b), c, 0, 0, 0);
}

// ---- weight transpose+convert: out[g][c][r] = bf16(in[g][r][c]) ----
__global__ __launch_bounds__(256) void k_transpose(const float* __restrict__ in,
                                                   unsigned short* __restrict__ out,
                                                   int R, int C) {
  __shared__ float t[64][65];
  const int g = blockIdx.y;
  const int nCt = C >> 6;
  const int tr = blockIdx.x / nCt;
  const int tc = blockIdx.x - tr * nCt;
  const int lw = threadIdx.x >> 6;
  const int lc = threadIdx.x & 63;
  const float* ip = in + (size_t)g * R * C + (size_t)(tr << 6) * C + (tc << 6);
#pragma unroll
  for (int i = 0; i < 16; ++i) {
    int r = (i << 2) + lw;
    t[r][lc] = ip[(size_t)r * C + lc];
  }
  __syncthreads();
  unsigned short* op = out + (size_t)g * R * C + (size_t)(tc << 6) * R + (tr << 6);
#pragma unroll
  for (int i = 0; i < 16; ++i) {
    int r = (i << 2) + lw;
    op[(size_t)r * R + lc] = f2bf(t[lc][r]);
  }
}

// Wa [512][18] -> WaT [18][512] f32
__global__ __launch_bounds__(256) void k_wat(const float* __restrict__ wa,
                                             float* __restrict__ wat) {
  int tid = blockIdx.x * 256 + threadIdx.x;
  if (tid < NG * ND) {
    int g = tid >> 9, d = tid & (ND - 1);
    wat[tid] = wa[d * NG + g];
  }
}

// attention weights w[B,G] = softmax(X@Wa+ba)*gv, plus X -> bf16
__global__ __launch_bounds__(256) void k_attn(const float* __restrict__ X,
                                              const float* __restrict__ GV,
                                              const float* __restrict__ wat,
                                              const float* __restrict__ ba,
                                              float* __restrict__ w,
                                              unsigned short* __restrict__ xb) {
  __shared__ float wl[NG * ND];
  const int tid = threadIdx.x;
  for (int i = tid; i < NG * ND; i += 256) wl[i] = wat[i];
  __syncthreads();
  const int lane = tid & 63;
  const int row = (blockIdx.x << 2) + (tid >> 6);
  const float* xr = X + (size_t)row * ND + (lane << 3);
  float x[8];
  {
    float4 a = *(const float4*)xr;
    float4 b = *(const float4*)(xr + 4);
    x[0] = a.x; x[1] = a.y; x[2] = a.z; x[3] = a.w;
    x[4] = b.x; x[5] = b.y; x[6] = b.z; x[7] = b.w;
  }
  {
    u4v p;
#pragma unroll
    for (int j = 0; j < 4; ++j)
      p[j] = (unsigned)f2bf(x[2 * j]) | ((unsigned)f2bf(x[2 * j + 1]) << 16);
    *(u4v*)(xb + (size_t)row * ND + (lane << 3)) = p;
  }
  float lg[NG];
#pragma unroll
  for (int g = 0; g < NG; ++g) {
    const float* wr = wl + g * ND + (lane << 3);
    float s = 0.f;
#pragma unroll
    for (int j = 0; j < 8; ++j) s += x[j] * wr[j];
    lg[g] = s;
  }
#pragma unroll
  for (int off = 32; off > 0; off >>= 1) {
#pragma unroll
    for (int g = 0; g < NG; ++g) lg[g] += __shfl_xor(lg[g], off);
  }
  float m = -3.4e38f;
#pragma unroll
  for (int g = 0; g < NG; ++g) { lg[g] += ba[g]; m = fmaxf(m, lg[g]); }
  float s = 0.f;
#pragma unroll
  for (int g = 0; g < NG; ++g) { lg[g] = expf(lg[g] - m); s += lg[g]; }
  float inv = 1.f / s;
  if (lane < NG) {
    float gv = GV[(size_t)row * NG + lane];
    w[(size_t)row * NG + lane] = gv > 0.f ? lg[lane] * inv * gv : 0.f;
  }
}

// fused experts + aggregation. 1 block = 64 rows, 8 waves.
__global__ __launch_bounds__(512) void k_main(
    const unsigned short* __restrict__ xb,    // [B][512] bf16
    const float* __restrict__ wbg,            // [B][18]
    const unsigned short* __restrict__ w1t,   // [18][256][512] bf16
    const unsigned short* __restrict__ w2t,   // [18][128][256]
    const unsigned short* __restrict__ w3t,   // [18][128][128]
    const unsigned short* __restrict__ waggt, // [512][640]
    const float* __restrict__ b1, const float* __restrict__ b2,
    const float* __restrict__ b3, const float* __restrict__ bagg,
    float* __restrict__ out) {
  __shared__ __align__(16) char smem[119808];
  char* const XT = smem;                 // [64][512] bf16, stride 1024B, swz
  char* const H1 = smem + 65536;         // [64][256] bf16, stride 512B, swz
  char* const H2 = smem + 98304;         // [64][128] bf16, stride 256B, swz
  float* const WL = (float*)(smem + 114688); // [64][20]

  const int tid = threadIdx.x;
  const int row0 = blockIdx.x << 6;

#pragma unroll
  for (int i = 0; i < 8; ++i) {
    int idx = (i << 9) + tid;
    int r = idx >> 6, c16 = idx & 63;
    u4v v = *(const u4v*)(xb + ((size_t)(row0 + r) << 9) + (c16 << 3));
    int byte = (r << 10) + (c16 << 4);
    *(u4v*)(XT + (byte ^ ((r & 7) << 4))) = v;
  }
  for (int i = tid; i < 64 * NG; i += 512) {
    int r = i / NG, g = i - r * NG;
    WL[r * 20 + g] = wbg[(size_t)(row0 + r) * NG + g];
  }
  __syncthreads();

  const int wid = tid >> 6, lane = tid & 63;
  const int lr = lane & 15, lk = lane >> 4;
  const int n1 = wid << 5;            // GEMM1 col base (8 waves x 32 = 256)
  const int mr0 = (wid >> 2) << 5;    // GEMM2/3 row base
  const int nc0 = (wid & 3) << 5;     // GEMM2/3 col base

  f4v racc[2][2];
#pragma unroll
  for (int i = 0; i < 2; ++i)
#pragma unroll
    for (int j = 0; j < 2; ++j) racc[i][j] = (f4v){0.f, 0.f, 0.f, 0.f};

  for (int g = 0; g < NG; ++g) {
    // ---------- GEMM1: h1 = relu(X @ W1[g] + b1[g])  [64,256] ----------
    const unsigned short* const w1g = w1t + (size_t)g * (NHH * ND);
    const float bv1[2] = {b1[g * NHH + n1 + lr], b1[g * NHH + n1 + 16 + lr]};
    f4v acc1[4][2];
#pragma unroll
    for (int mi = 0; mi < 4; ++mi)
#pragma unroll
      for (int ni = 0; ni < 2; ++ni) acc1[mi][ni] = (f4v){0.f, 0.f, 0.f, 0.f};
    for (int ks = 0; ks < 16; ++ks) {
      const int cb = (ks << 6) + (lk << 4);
      s8v a[4], bb[2];
#pragma unroll
      for (int mi = 0; mi < 4; ++mi) {
        const int row = (mi << 4) + lr;
        a[mi] = *(const s8v*)(XT + (((row << 10) + cb) ^ ((row & 7) << 4)));
      }
#pragma unroll
      for (int ni = 0; ni < 2; ++ni)
        bb[ni] = *(const s8v*)(w1g + ((size_t)(n1 + (ni << 4) + lr) << 9) +
                               (ks << 5) + (lk << 3));
#pragma unroll
      for (int mi = 0; mi < 4; ++mi)
#pragma unroll
        for (int ni = 0; ni < 2; ++ni)
          acc1[mi][ni] = mfma16(a[mi], bb[ni], acc1[mi][ni]);
    }
#pragma unroll
    for (int mi = 0; mi < 4; ++mi)
#pragma unroll
      for (int ni = 0; ni < 2; ++ni)
#pragma unroll
        for (int r = 0; r < 4; ++r) {
          const int row = (mi << 4) + (lk << 2) + r;
          const int col = n1 + (ni << 4) + lr;
          float v = fmaxf(acc1[mi][ni][r] + bv1[ni], 0.f);
          const int byte = (row << 9) + (col << 1);
          *(unsigned short*)(H1 + (byte ^ ((row & 7) << 4))) = f2bf(v);
        }
    __syncthreads();

    // ---------- GEMM2: h2 = relu(h1 @ W2[g] + b2[g])  [64,128] ----------
    const unsigned short* const w2g = w2t + (size_t)g * (NH * NHH);
    const float bv2[2] = {b2[g * NH + nc0 + lr], b2[g * NH + nc0 + 16 + lr]};
    f4v acc2[2][2];
#pragma unroll
    for (int mi = 0; mi < 2; ++mi)
#pragma unroll
      for (int ni = 0; ni < 2; ++ni) acc2[mi][ni] = (f4v){0.f, 0.f, 0.f, 0.f};
    for (int ks = 0; ks < 8; ++ks) {
      const int cb = (ks << 6) + (lk << 4);
      s8v a[2], bb[2];
#pragma unroll
      for (int mi = 0; mi < 2; ++mi) {
        const int row = mr0 + (mi << 4) + lr;
        a[mi] = *(const s8v*)(H1 + (((row << 9) + cb) ^ ((row & 7) << 4)));
      }
#pragma unroll
      for (int ni = 0; ni < 2; ++ni)
        bb[ni] = *(const s8v*)(w2g + ((size_t)(nc0 + (ni << 4) + lr) << 8) +
                               (ks << 5) + (lk << 3));
#pragma unroll
      for (int mi = 0; mi < 2; ++mi)
#pragma unroll
        for (int ni = 0; ni < 2; ++ni)
          acc2[mi][ni] = mfma16(a[mi], bb[ni], acc2[mi][ni]);
    }
#pragma unroll
    for (int mi = 0; mi < 2; ++mi)
#pragma unroll
      for (int ni = 0; ni < 2; ++ni)
#pragma unroll
        for (int r = 0; r < 4; ++r) {
          const int row = mr0 + (mi << 4) + (lk << 2) + r;
          const int col = nc0 + (ni << 4) + lr;
          float v = fmaxf(acc2[mi][ni][r] + bv2[ni], 0.f);
          const int byte = (row << 8) + (col << 1);
          *(unsigned short*)(H2 + (byte ^ ((row & 7) << 4))) = f2bf(v);
        }
    __syncthreads();

    // ---------- GEMM3: h3 = h2 @ W3[g] + b3[g]; racc += w*h3 ----------
    const unsigned short* const w3g = w3t + (size_t)g * (NH * NH);
    const float bv3[2] = {b3[g * NH + nc0 + lr], b3[g * NH + nc0 + 16 + lr]};
    f4v acc3[2][2];
#pragma unroll
    for (int mi = 0; mi < 2; ++mi)
#pragma unroll
      for (int ni = 0; ni < 2; ++ni) acc3[mi][ni] = (f4v){0.f, 0.f, 0.f, 0.f};
    for (int ks = 0; ks < 4; ++ks) {
      const int cb = (ks << 6) + (lk << 4);
      s8v a[2], bb[2];
#pragma unroll
      for (int mi = 0; mi < 2; ++mi) {
        const int row = mr0 + (mi << 4) + lr;
        a[mi] = *(const s8v*)(H2 + (((row << 8) + cb) ^ ((row & 7) << 4)));
      }
#pragma unroll
      for (int ni = 0; ni < 2; ++ni)
        bb[ni] = *(const s8v*)(w3g + ((size_t)(nc0 + (ni << 4) + lr) << 7) +
                               (ks << 5) + (lk << 3));
#pragma unroll
      for (int mi = 0; mi < 2; ++mi)
#pragma unroll
        for (int ni = 0; ni < 2; ++ni)
          acc3[mi][ni] = mfma16(a[mi], bb[ni], acc3[mi][ni]);
    }
#pragma unroll
    for (int mi = 0; mi < 2; ++mi)
#pragma unroll
      for (int ni = 0; ni < 2; ++ni)
#pragma unroll
        for (int r = 0; r < 4; ++r) {
          const int row = mr0 + (mi << 4) + (lk << 2) + r;
          const float wv = WL[row * 20 + g];
          racc[mi][ni][r] += wv * (acc3[mi][ni][r] + bv3[ni]);
        }
  }

  __syncthreads();  // all GEMM3 H2 reads done before overwrite with ref
#pragma unroll
  for (int mi = 0; mi < 2; ++mi)
#pragma unroll
    for (int ni = 0; ni < 2; ++ni)
#pragma unroll
      for (int r = 0; r < 4; ++r) {
        const int row = mr0 + (mi << 4) + (lk << 2) + r;
        const int col = nc0 + (ni << 4) + lr;
        const int byte = (row << 8) + (col << 1);
        *(unsigned short*)(H2 + (byte ^ ((row & 7) << 4))) = f2bf(racc[mi][ni][r]);
      }
  __syncthreads();

  // ---------- GEMM4: out = relu([X | ref] @ Wagg + bagg)  [64,512] ----------
  const int n4 = wid << 6;
  float bv4[4];
#pragma unroll
  for (int ni = 0; ni < 4; ++ni) bv4[ni] = bagg[n4 + (ni << 4) + lr];
  f4v acc4[4][4];
#pragma unroll
  for (int mi = 0; mi < 4; ++mi)
#pragma unroll
    for (int ni = 0; ni < 4; ++ni) acc4[mi][ni] = (f4v){0.f, 0.f, 0.f, 0.f};
  for (int ks = 0; ks < 20; ++ks) {
    s8v a[4], bb[4];
    if (ks < 16) {
      const int cb = (ks << 6) + (lk << 4);
#pragma unroll
      for (int mi = 0; mi < 4; ++mi) {
        const int row = (mi << 4) + lr;
        a[mi] = *(const s8v*)(XT + (((row << 10) + cb) ^ ((row & 7) << 4)));
      }
    } else {
      const int cb = ((ks - 16) << 6) + (lk << 4);
#pragma unroll
      for (int mi = 0; mi < 4; ++mi) {
        const int row = (mi << 4) + lr;
        a[mi] = *(const s8v*)(H2 + (((row << 8) + cb) ^ ((row & 7) << 4)));
      }
    }
#pragma unroll
    for (int ni = 0; ni < 4; ++ni)
      bb[ni] = *(const s8v*)(waggt + (size_t)(n4 + (ni << 4) + lr) * 640 +
                             (ks << 5) + (lk << 3));
#pragma unroll
    for (int mi = 0; mi < 4; ++mi)
#pragma unroll
      for (int ni = 0; ni < 4; ++ni)
        acc4[mi][ni] = mfma16(a[mi], bb[ni], acc4[mi][ni]);
  }
#pragma unroll
  for (int mi = 0; mi < 4; ++mi)
#pragma unroll
    for (int ni = 0; ni < 4; ++ni)
#pragma unroll
      for (int r = 0; r < 4; ++r) {
        const int row = (mi << 4) + (lk << 2) + r;
        const int col = n4 + (ni << 4) + lr;
        float v = acc4[mi][ni][r] + bv4[ni];
        out[((size_t)(row0 + row) << 9) + col] = fmaxf(v, 0.f);
      }
}

// ---------------- workspace layout (bytes) ----------------
#define OFF_W     0u          // w[B][18] f32        : 1179648
#define OFF_XB    1179648u    // xb[B][512] bf16     : 16777216
#define OFF_W1T   17956864u   // [18][256][512] bf16 : 4718592
#define OFF_W2T   22675456u   // [18][128][256] bf16 : 1179648
#define OFF_W3T   23855104u   // [18][128][128] bf16 : 589824
#define OFF_WAGGT 24444928u   // [512][640] bf16     : 655360
#define OFF_WAT   25100288u   // [18][512] f32       : 36864  (end 25137152)

extern "C" void kernel_launch(void* const* d_in, const int* in_sizes, int n_in,
                              void* d_out, int out_size, void* d_ws, size_t ws_size,
                              hipStream_t stream) {
  const float* X    = (const float*)d_in[0];
  const float* GV   = (const float*)d_in[1];
  const float* W1   = (const float*)d_in[2];
  const float* b1   = (const float*)d_in[3];
  const float* W2   = (const float*)d_in[4];
  const float* b2   = (const float*)d_in[5];
  const float* W3   = (const float*)d_in[6];
  const float* b3   = (const float*)d_in[7];
  const float* Wa   = (const float*)d_in[8];
  const float* ba   = (const float*)d_in[9];
  const float* Wagg = (const float*)d_in[10];
  const float* bagg = (const float*)d_in[11];
  float* out = (float*)d_out;
  char* ws = (char*)d_ws;

  float* w_ws           = (float*)(ws + OFF_W);
  unsigned short* xb    = (unsigned short*)(ws + OFF_XB);
  unsigned short* w1t   = (unsigned short*)(ws + OFF_W1T);
  unsigned short* w2t   = (unsigned short*)(ws + OFF_W2T);
  unsigned short* w3t   = (unsigned short*)(ws + OFF_W3T);
  unsigned short* waggt = (unsigned short*)(ws + OFF_WAGGT);
  float* wat            = (float*)(ws + OFF_WAT);

  k_transpose<<<dim3(32, 18), 256, 0, stream>>>(W1, w1t, 512, 256);
  k_transpose<<<dim3(8, 18), 256, 0, stream>>>(W2, w2t, 256, 128);
  k_transpose<<<dim3(4, 18), 256, 0, stream>>>(W3, w3t, 128, 128);
  k_transpose<<<dim3(80, 1), 256, 0, stream>>>(Wagg, waggt, 640, 512);
  k_wat<<<36, 256, 0, stream>>>(Wa, wat);
  k_attn<<<4096, 256, 0, stream>>>(X, GV, wat, ba, w_ws, xb);
  k_main<<<256, 512, 0, stream>>>(xb, w_ws, w1t, w2t, w3t, waggt,
                                  b1, b2, b3, bagg, out);
}